// Round 3
// baseline (405.773 us; speedup 1.0000x reference)
//
#include <hip/hip_runtime.h>
#include <hip/hip_bf16.h>
#include <cstdint>

typedef unsigned short ushort_t;
typedef unsigned int uint_t;
typedef __bf16 bf16x8 __attribute__((ext_vector_type(8)));
typedef float f32x4 __attribute__((ext_vector_type(4)));

#define B_SZ 32
#define C_IN 256
#define C_OUT 256
#define H_SZ 56
#define W_SZ 56
#define HW 3136          // 56*56
#define HP 58            // padded H (halo 1 each side)
#define WP 58            // padded W
#define BN_EPS 1e-5f
#define K_ZERO 128

__device__ __forceinline__ ushort_t f2bf(float f) {
    unsigned int u = __builtin_bit_cast(unsigned int, f);
    unsigned int r = (u + 0x7fffu + ((u >> 16) & 1u)) >> 16;
    return (ushort_t)r;
}

__device__ __forceinline__ void load_lds16(const void* gptr, void* ldsptr) {
    __builtin_amdgcn_global_load_lds(
        (const __attribute__((address_space(1))) unsigned int*)(uintptr_t)gptr,
        (__attribute__((address_space(3))) unsigned int*)(uintptr_t)ldsptr,
        16, 0, 0);
}

// ---------------------------------------------------------------------------
// Kernel 1: weights OIHW fp32 -> Wt[tap][co][ci] bf16; BN consts; zero s.
// grid: 2304 blocks, 256
// ---------------------------------------------------------------------------
__global__ __launch_bounds__(256) void prep_w_kernel(const float* __restrict__ w,
                                                     const float* __restrict__ gamma,
                                                     const float* __restrict__ beta,
                                                     const float* __restrict__ mean,
                                                     const float* __restrict__ var,
                                                     ushort_t* __restrict__ Wt,
                                                     float* __restrict__ bninv,
                                                     float* __restrict__ bnadd,
                                                     float* __restrict__ s) {
    int idx = blockIdx.x * 256 + threadIdx.x;
    if (idx < 9 * C_OUT * C_IN) {
        int tap = idx >> 16;
        int rem = idx & 65535;
        int co = rem >> 8, ci = rem & 255;
        Wt[idx] = f2bf(w[(size_t)(co * C_IN + ci) * 9 + tap]);
    }
    if (blockIdx.x < 32) s[idx] = 0.f;  // zero the 8192-float abs-mean acc
    if (blockIdx.x == 32 && threadIdx.x < C_OUT) {
        int c = threadIdx.x;
        float inv = gamma[c] * rsqrtf(var[c] + BN_EPS);
        bninv[c] = inv;
        bnadd[c] = beta[c] - mean[c] * inv;
    }
}

// ---------------------------------------------------------------------------
// Kernel 2: x NCHW fp32 -> padded NHWC bf16, fused abs-mean partials,
// fused halo zeroing (replaces the 55 MB memset).
// grid: (4 ci-tiles, 56 h, 32 b), block 256
// ---------------------------------------------------------------------------
__global__ __launch_bounds__(256) void prep_x_kernel(const float* __restrict__ x,
                                                     ushort_t* __restrict__ xbp,
                                                     float* __restrict__ s) {
    const int cit = blockIdx.x, h = blockIdx.y, b = blockIdx.z;
    __shared__ float tile[64][57];
    __shared__ float red2[256];
    const int t = threadIdx.x;
    const float* src = x + ((size_t)(b * C_IN + cit * 64) * H_SZ + h) * W_SZ;
    for (int i = t; i < 64 * 14; i += 256) {
        int ci = i / 14, w4 = (i - ci * 14) * 4;
        float4 v = *(const float4*)(src + (size_t)ci * HW + w4);
        tile[ci][w4] = v.x; tile[ci][w4 + 1] = v.y;
        tile[ci][w4 + 2] = v.z; tile[ci][w4 + 3] = v.w;
    }
    __syncthreads();
    {
        int ci = t & 63, wg = t >> 6;
        float a = 0.f;
#pragma unroll
        for (int j = 0; j < 14; j++) a += fabsf(tile[ci][wg * 14 + j]);
        red2[t] = a;
    }
    __syncthreads();
    if (t < 64) {
        float tot = red2[t] + red2[t + 64] + red2[t + 128] + red2[t + 192];
        atomicAdd(&s[b * C_IN + cit * 64 + t], tot * (1.0f / (float)HW));
    }
    // interior write: 4 ci per thread -> 8B stores, coalesced along ci
    const uint2 z2 = make_uint2(0u, 0u);
    for (int i = t; i < W_SZ * 16; i += 256) {
        int w = i >> 4, c4 = (i & 15) * 4;
        uint_t lo = (uint_t)f2bf(tile[c4][w])     | ((uint_t)f2bf(tile[c4 + 1][w]) << 16);
        uint_t hi = (uint_t)f2bf(tile[c4 + 2][w]) | ((uint_t)f2bf(tile[c4 + 3][w]) << 16);
        size_t dst = ((size_t)((b * HP + h + 1) * WP + (w + 1))) * C_IN + cit * 64 + c4;
        *(uint2*)&xbp[dst] = make_uint2(lo, hi);
    }
    // halo: left/right column of this padded row
    if (t < 32) {
        int side = t >> 4, c4 = (t & 15) * 4;
        size_t dst = ((size_t)((b * HP + h + 1) * WP + side * 57)) * C_IN + cit * 64 + c4;
        *(uint2*)&xbp[dst] = z2;
    }
    // halo: full top (h==0) / bottom (h==55) padded rows
    if (h == 0 || h == 55) {
        int prow = (h == 0) ? 0 : 57;
        for (int i = t; i < 58 * 16; i += 256) {
            int w = i >> 4, c4 = (i & 15) * 4;
            size_t dst = ((size_t)((b * HP + prow) * WP + w)) * C_IN + cit * 64 + c4;
            *(uint2*)&xbp[dst] = z2;
        }
    }
}

// ---------------------------------------------------------------------------
// Kernel 3: gate
// ---------------------------------------------------------------------------
__global__ __launch_bounds__(256) void gate_kernel(const float* __restrict__ s,
                                                   const float* __restrict__ gw,
                                                   const float* __restrict__ gb,
                                                   float* __restrict__ tscale) {
    const int b = blockIdx.x, t = threadIdx.x;
    __shared__ float sh_s[C_IN], sh_g[C_OUT], red[256];
    sh_s[t] = s[b * C_IN + t];
    __syncthreads();
    float acc = gb[t];
    const float* wr = gw + (size_t)t * C_IN;
    for (int ci = 0; ci < C_IN; ci++) acc += sh_s[ci] * wr[ci];
    float g = fmaxf(acc, 0.f);
    sh_g[t] = g;
    __syncthreads();
    int cnt = 0;
    for (int j = 0; j < C_OUT; j++) {
        float gj = sh_g[j];
        cnt += (gj < g) || (gj == g && j < t);
    }
    float tv = (cnt >= K_ZERO) ? g : 0.f;
    red[t] = tv;
    __syncthreads();
    for (int off = 128; off > 0; off >>= 1) {
        if (t < off) red[t] += red[t + off];
        __syncthreads();
    }
    tscale[b * C_OUT + t] = tv * ((float)C_OUT / red[0]);
}

// ---------------------------------------------------------------------------
// Kernel 4: implicit-GEMM conv + BN + ReLU + channel scale
// Tile 128(p) x 256(co = ALL of C_OUT -> x staged once per p-tile).
// 4 waves, each 64x128 via 4x8 16x16x32 MFMAs (64 MFMA per barrier interval).
// BK=64 (one tap, 64 ci). global_load_lds w=16, XOR swizzle in global addr.
// grid: 784, block 256, __launch_bounds__(256,2) -> <=256 VGPR, 2 blocks/CU
// ---------------------------------------------------------------------------
__global__ __launch_bounds__(256, 2) void conv_kernel(const ushort_t* __restrict__ xbp,
                                                      const ushort_t* __restrict__ Wt,
                                                      const float* __restrict__ bninv,
                                                      const float* __restrict__ bnadd,
                                                      const float* __restrict__ tscale,
                                                      float* __restrict__ out) {
    __shared__ __align__(16) ushort_t As[128 * 64];  // 16 KB
    __shared__ __align__(16) ushort_t Bs[256 * 64];  // 32 KB
    const int t = threadIdx.x;
    const int bx = blockIdx.x;  // p tile
    const int lane = t & 63;
    const int wv = t >> 6;
    const int waveM = wv >> 1, waveN = wv & 1;  // M halves of 64, N halves of 128

    // staging: chunk q = i*256+t -> row i*32+(t>>3), stored col t&7,
    // global col (t&7)^(row&7); i*32 == 0 mod 8 so row&7 == (t>>3)&7.
    const int srow = t >> 3;
    const int gxor8 = ((t & 7) ^ (srow & 7)) * 8;
    int arow[4], wrow[8];
#pragma unroll
    for (int i = 0; i < 4; i++) {
        int p = bx * 128 + i * 32 + srow;
        int b = p / HW;
        int r = p - b * HW;
        int hh = r / W_SZ, ww = r - hh * W_SZ;
        arow[i] = ((b * HP + hh + 1) * WP + (ww + 1)) * C_IN + gxor8;
    }
#pragma unroll
    for (int i = 0; i < 8; i++) wrow[i] = (i * 32 + srow) * C_IN + gxor8;
    ushort_t* ldsA = As + t * 8;
    ushort_t* ldsB = Bs + t * 8;

    // fragment LDS byte offsets: row r, global chunk c stored at c^(r&7)
    int aoff[2][4], boff[2][8];
#pragma unroll
    for (int ks = 0; ks < 2; ks++) {
        int c = (lane >> 4) + ks * 4;
#pragma unroll
        for (int mt = 0; mt < 4; mt++) {
            int ra = waveM * 64 + mt * 16 + (lane & 15);
            aoff[ks][mt] = (ra * 8 + (c ^ (ra & 7))) * 16;
        }
#pragma unroll
        for (int nt = 0; nt < 8; nt++) {
            int rb = waveN * 128 + nt * 16 + (lane & 15);
            boff[ks][nt] = (rb * 8 + (c ^ (rb & 7))) * 16;
        }
    }

    f32x4 acc[4][8];
#pragma unroll
    for (int i = 0; i < 4; i++)
#pragma unroll
        for (int j = 0; j < 8; j++) acc[i][j] = (f32x4){0.f, 0.f, 0.f, 0.f};

    const char* Ab = (const char*)As;
    const char* Bb = (const char*)Bs;

    for (int tap = 0; tap < 9; tap++) {
        const int doff = ((tap / 3 - 1) * WP + (tap % 3 - 1)) * C_IN;
        const int woff = tap * (C_OUT * C_IN);
#pragma unroll
        for (int cq = 0; cq < 4; cq++) {
            const int ci0 = cq * 64;
#pragma unroll
            for (int i = 0; i < 4; i++)
                load_lds16(xbp + arow[i] + doff + ci0, ldsA + i * 2048);
#pragma unroll
            for (int i = 0; i < 8; i++)
                load_lds16(Wt + wrow[i] + woff + ci0, ldsB + i * 2048);
            __syncthreads();
#pragma unroll
            for (int ks = 0; ks < 2; ks++) {
                bf16x8 af[4], bf[8];
#pragma unroll
                for (int mt = 0; mt < 4; mt++) af[mt] = *(const bf16x8*)(Ab + aoff[ks][mt]);
#pragma unroll
                for (int nt = 0; nt < 8; nt++) bf[nt] = *(const bf16x8*)(Bb + boff[ks][nt]);
#pragma unroll
                for (int mt = 0; mt < 4; mt++)
#pragma unroll
                    for (int nt = 0; nt < 8; nt++)
                        acc[mt][nt] = __builtin_amdgcn_mfma_f32_16x16x32_bf16(
                            af[mt], bf[nt], acc[mt][nt], 0, 0, 0);
            }
            __syncthreads();
        }
    }

    // epilogue
#pragma unroll
    for (int mt = 0; mt < 4; mt++) {
        int p0 = bx * 128 + waveM * 64 + mt * 16 + (lane >> 4) * 4;
        int b = p0 / HW;
        int hw = p0 - b * HW;
#pragma unroll
        for (int nt = 0; nt < 8; nt++) {
            int co = waveN * 128 + nt * 16 + (lane & 15);
            float inv = bninv[co], add = bnadd[co], tsc = tscale[b * C_OUT + co];
            float4 o;
            o.x = fmaxf(acc[mt][nt][0] * inv + add, 0.f) * tsc;
            o.y = fmaxf(acc[mt][nt][1] * inv + add, 0.f) * tsc;
            o.z = fmaxf(acc[mt][nt][2] * inv + add, 0.f) * tsc;
            o.w = fmaxf(acc[mt][nt][3] * inv + add, 0.f) * tsc;
            *(float4*)(out + (size_t)(b * C_OUT + co) * HW + hw) = o;
        }
    }
}

// ---------------------------------------------------------------------------
extern "C" void kernel_launch(void* const* d_in, const int* in_sizes, int n_in,
                              void* d_out, int out_size, void* d_ws, size_t ws_size,
                              hipStream_t stream) {
    const float* x      = (const float*)d_in[0];
    const float* conv_w = (const float*)d_in[1];
    const float* gate_w = (const float*)d_in[2];
    const float* gate_b = (const float*)d_in[3];
    const float* bn_g   = (const float*)d_in[4];
    const float* bn_b   = (const float*)d_in[5];
    const float* bn_m   = (const float*)d_in[6];
    const float* bn_v   = (const float*)d_in[7];
    float* out = (float*)d_out;

    char* ws = (char*)d_ws;
    float*    s      = (float*)(ws + 0);          // 8192 f
    float*    tscale = (float*)(ws + 32768);      // 8192 f
    float*    bninv  = (float*)(ws + 65536);      // 256 f
    float*    bnadd  = (float*)(ws + 66560);      // 256 f
    ushort_t* Wt     = (ushort_t*)(ws + 67584);   // 589824 bf16
    ushort_t* xbp    = (ushort_t*)(ws + 1247232); // 32*58*58*256 bf16

    prep_w_kernel<<<2304, 256, 0, stream>>>(conv_w, bn_g, bn_b, bn_m, bn_v, Wt, bninv, bnadd, s);
    prep_x_kernel<<<dim3(4, 56, 32), 256, 0, stream>>>(x, xbp, s);
    gate_kernel<<<32, 256, 0, stream>>>(s, gate_w, gate_b, tscale);
    conv_kernel<<<784, 256, 0, stream>>>(xbp, Wt, bninv, bnadd, tscale, out);
}

// Round 4
// 350.376 us; speedup vs baseline: 1.1581x; 1.1581x over previous
//
#include <hip/hip_runtime.h>
#include <hip/hip_bf16.h>
#include <cstdint>

typedef unsigned short ushort_t;
typedef unsigned int uint_t;
typedef __bf16 bf16x8 __attribute__((ext_vector_type(8)));
typedef float f32x4 __attribute__((ext_vector_type(4)));

#define B_SZ 32
#define C_IN 256
#define C_OUT 256
#define H_SZ 56
#define W_SZ 56
#define HW 3136          // 56*56
#define HP 58            // padded H (halo 1 each side)
#define WP 58            // padded W
#define BN_EPS 1e-5f
#define K_ZERO 128

__device__ __forceinline__ ushort_t f2bf(float f) {
    unsigned int u = __builtin_bit_cast(unsigned int, f);
    unsigned int r = (u + 0x7fffu + ((u >> 16) & 1u)) >> 16;
    return (ushort_t)r;
}

__device__ __forceinline__ void load_lds16(const void* gptr, void* ldsptr) {
    __builtin_amdgcn_global_load_lds(
        (const __attribute__((address_space(1))) unsigned int*)(uintptr_t)gptr,
        (__attribute__((address_space(3))) unsigned int*)(uintptr_t)ldsptr,
        16, 0, 0);
}

// ---------------------------------------------------------------------------
// Kernel 1: weights OIHW fp32 -> Wt[tap][co][ci] bf16; BN consts; zero s.
// ---------------------------------------------------------------------------
__global__ __launch_bounds__(256) void prep_w_kernel(const float* __restrict__ w,
                                                     const float* __restrict__ gamma,
                                                     const float* __restrict__ beta,
                                                     const float* __restrict__ mean,
                                                     const float* __restrict__ var,
                                                     ushort_t* __restrict__ Wt,
                                                     float* __restrict__ bninv,
                                                     float* __restrict__ bnadd,
                                                     float* __restrict__ s) {
    int idx = blockIdx.x * 256 + threadIdx.x;
    if (idx < 9 * C_OUT * C_IN) {
        int tap = idx >> 16;
        int rem = idx & 65535;
        int co = rem >> 8, ci = rem & 255;
        Wt[idx] = f2bf(w[(size_t)(co * C_IN + ci) * 9 + tap]);
    }
    if (blockIdx.x < 32) s[idx] = 0.f;
    if (blockIdx.x == 32 && threadIdx.x < C_OUT) {
        int c = threadIdx.x;
        float inv = gamma[c] * rsqrtf(var[c] + BN_EPS);
        bninv[c] = inv;
        bnadd[c] = beta[c] - mean[c] * inv;
    }
}

// ---------------------------------------------------------------------------
// Kernel 2: x NCHW fp32 -> padded NHWC bf16, fused abs-mean partials + halo.
// grid: (4 ci-tiles, 56 h, 32 b), block 256
// ---------------------------------------------------------------------------
__global__ __launch_bounds__(256) void prep_x_kernel(const float* __restrict__ x,
                                                     ushort_t* __restrict__ xbp,
                                                     float* __restrict__ s) {
    const int cit = blockIdx.x, h = blockIdx.y, b = blockIdx.z;
    __shared__ float tile[64][57];
    __shared__ float red2[256];
    const int t = threadIdx.x;
    const float* src = x + ((size_t)(b * C_IN + cit * 64) * H_SZ + h) * W_SZ;
    for (int i = t; i < 64 * 14; i += 256) {
        int ci = i / 14, w4 = (i - ci * 14) * 4;
        float4 v = *(const float4*)(src + (size_t)ci * HW + w4);
        tile[ci][w4] = v.x; tile[ci][w4 + 1] = v.y;
        tile[ci][w4 + 2] = v.z; tile[ci][w4 + 3] = v.w;
    }
    __syncthreads();
    {
        int ci = t & 63, wg = t >> 6;
        float a = 0.f;
#pragma unroll
        for (int j = 0; j < 14; j++) a += fabsf(tile[ci][wg * 14 + j]);
        red2[t] = a;
    }
    __syncthreads();
    if (t < 64) {
        float tot = red2[t] + red2[t + 64] + red2[t + 128] + red2[t + 192];
        atomicAdd(&s[b * C_IN + cit * 64 + t], tot * (1.0f / (float)HW));
    }
    const uint2 z2 = make_uint2(0u, 0u);
    for (int i = t; i < W_SZ * 16; i += 256) {
        int w = i >> 4, c4 = (i & 15) * 4;
        uint_t lo = (uint_t)f2bf(tile[c4][w])     | ((uint_t)f2bf(tile[c4 + 1][w]) << 16);
        uint_t hi = (uint_t)f2bf(tile[c4 + 2][w]) | ((uint_t)f2bf(tile[c4 + 3][w]) << 16);
        size_t dst = ((size_t)((b * HP + h + 1) * WP + (w + 1))) * C_IN + cit * 64 + c4;
        *(uint2*)&xbp[dst] = make_uint2(lo, hi);
    }
    if (t < 32) {
        int side = t >> 4, c4 = (t & 15) * 4;
        size_t dst = ((size_t)((b * HP + h + 1) * WP + side * 57)) * C_IN + cit * 64 + c4;
        *(uint2*)&xbp[dst] = z2;
    }
    if (h == 0 || h == 55) {
        int prow = (h == 0) ? 0 : 57;
        for (int i = t; i < 58 * 16; i += 256) {
            int w = i >> 4, c4 = (i & 15) * 4;
            size_t dst = ((size_t)((b * HP + prow) * WP + w)) * C_IN + cit * 64 + c4;
            *(uint2*)&xbp[dst] = z2;
        }
    }
}

// ---------------------------------------------------------------------------
// Kernel 3: gate
// ---------------------------------------------------------------------------
__global__ __launch_bounds__(256) void gate_kernel(const float* __restrict__ s,
                                                   const float* __restrict__ gw,
                                                   const float* __restrict__ gb,
                                                   float* __restrict__ tscale) {
    const int b = blockIdx.x, t = threadIdx.x;
    __shared__ float sh_s[C_IN], sh_g[C_OUT], red[256];
    sh_s[t] = s[b * C_IN + t];
    __syncthreads();
    float acc = gb[t];
    const float* wr = gw + (size_t)t * C_IN;
    for (int ci = 0; ci < C_IN; ci++) acc += sh_s[ci] * wr[ci];
    float g = fmaxf(acc, 0.f);
    sh_g[t] = g;
    __syncthreads();
    int cnt = 0;
    for (int j = 0; j < C_OUT; j++) {
        float gj = sh_g[j];
        cnt += (gj < g) || (gj == g && j < t);
    }
    float tv = (cnt >= K_ZERO) ? g : 0.f;
    red[t] = tv;
    __syncthreads();
    for (int off = 128; off > 0; off >>= 1) {
        if (t < off) red[t] += red[t + off];
        __syncthreads();
    }
    tscale[b * C_OUT + t] = tv * ((float)C_OUT / red[0]);
}

// ---------------------------------------------------------------------------
// Kernel 4: implicit-GEMM conv + BN + ReLU + channel scale
// M128 x N128 tile (r2 shape, acc 64/wave) at 3 blocks/CU (12 waves) —
// launch_bounds(256,3) caps regs at 170/wave so barrier drains are hidden
// by cross-block wave overlap (m97 ran 164 regs / 3 blocks).
// Grid 1568 swizzled: bx, bx+8 = same p-tile, both co halves -> same XCD
// under round-robin %8 dispatch -> A-tile read twice from the same L2.
// ---------------------------------------------------------------------------
__global__ __launch_bounds__(256, 3) void conv_kernel(const ushort_t* __restrict__ xbp,
                                                      const ushort_t* __restrict__ Wt,
                                                      const float* __restrict__ bninv,
                                                      const float* __restrict__ bnadd,
                                                      const float* __restrict__ tscale,
                                                      float* __restrict__ out) {
    __shared__ __align__(16) ushort_t As[128 * 64];  // 16 KB
    __shared__ __align__(16) ushort_t Bs[128 * 64];  // 16 KB
    const int t = threadIdx.x;
    // swizzle: bx = 16q + r -> p-tile 8q + (r&7), co-tile (r>>3)&1
    const int bxr = blockIdx.x;
    const int bx = (bxr >> 4) * 8 + (bxr & 7);   // p tile 0..783
    const int by = (bxr >> 3) & 1;               // co tile 0..1
    const int lane = t & 63;
    const int wv = t >> 6;
    const int waveM = wv >> 1, waveN = wv & 1;

    // staging: chunk q = i*256+t -> row i*32+(t>>3), stored col t&7,
    // global col (t&7)^(row&7)
    const int srow = t >> 3;
    const int gxor8 = ((t & 7) ^ (srow & 7)) * 8;
    int arow[4], wrow[4];
#pragma unroll
    for (int i = 0; i < 4; i++) {
        int p = bx * 128 + i * 32 + srow;
        int b = p / HW;
        int r = p - b * HW;
        int hh = r / W_SZ, ww = r - hh * W_SZ;
        arow[i] = ((b * HP + hh + 1) * WP + (ww + 1)) * C_IN + gxor8;
        wrow[i] = (by * 128 + i * 32 + srow) * C_IN + gxor8;
    }
    ushort_t* ldsA = As + t * 8;
    ushort_t* ldsB = Bs + t * 8;

    // fragment LDS byte offsets: row r, global chunk c stored at c^(r&7)
    int aoff[2][4], boff[2][4];
#pragma unroll
    for (int ks = 0; ks < 2; ks++) {
        int c = (lane >> 4) + ks * 4;
#pragma unroll
        for (int mt = 0; mt < 4; mt++) {
            int ra = waveM * 64 + mt * 16 + (lane & 15);
            aoff[ks][mt] = (ra * 8 + (c ^ (ra & 7))) * 16;
            int rb = waveN * 64 + mt * 16 + (lane & 15);
            boff[ks][mt] = (rb * 8 + (c ^ (rb & 7))) * 16;
        }
    }

    f32x4 acc[4][4];
#pragma unroll
    for (int i = 0; i < 4; i++)
#pragma unroll
        for (int j = 0; j < 4; j++) acc[i][j] = (f32x4){0.f, 0.f, 0.f, 0.f};

    const char* Ab = (const char*)As;
    const char* Bb = (const char*)Bs;

    for (int tap = 0; tap < 9; tap++) {
        const int doff = ((tap / 3 - 1) * WP + (tap % 3 - 1)) * C_IN;
        const int woff = tap * (C_OUT * C_IN);
#pragma unroll
        for (int cq = 0; cq < 4; cq++) {
            const int ci0 = cq * 64;
#pragma unroll
            for (int i = 0; i < 4; i++) {
                load_lds16(xbp + arow[i] + doff + ci0, ldsA + i * 2048);
                load_lds16(Wt + wrow[i] + woff + ci0, ldsB + i * 2048);
            }
            __syncthreads();
#pragma unroll
            for (int ks = 0; ks < 2; ks++) {
                bf16x8 af[4], bf[4];
#pragma unroll
                for (int mt = 0; mt < 4; mt++) af[mt] = *(const bf16x8*)(Ab + aoff[ks][mt]);
#pragma unroll
                for (int nt = 0; nt < 4; nt++) bf[nt] = *(const bf16x8*)(Bb + boff[ks][nt]);
#pragma unroll
                for (int mt = 0; mt < 4; mt++)
#pragma unroll
                    for (int nt = 0; nt < 4; nt++)
                        acc[mt][nt] = __builtin_amdgcn_mfma_f32_16x16x32_bf16(
                            af[mt], bf[nt], acc[mt][nt], 0, 0, 0);
            }
            __syncthreads();
        }
    }

    // epilogue: y = relu(acc*inv + add) * tscale; out NCHW fp32, float4 on p
#pragma unroll
    for (int mt = 0; mt < 4; mt++) {
        int p0 = bx * 128 + waveM * 64 + mt * 16 + (lane >> 4) * 4;
        int b = p0 / HW;
        int hw = p0 - b * HW;
#pragma unroll
        for (int nt = 0; nt < 4; nt++) {
            int co = by * 128 + waveN * 64 + nt * 16 + (lane & 15);
            float inv = bninv[co], add = bnadd[co], tsc = tscale[b * C_OUT + co];
            float4 o;
            o.x = fmaxf(acc[mt][nt][0] * inv + add, 0.f) * tsc;
            o.y = fmaxf(acc[mt][nt][1] * inv + add, 0.f) * tsc;
            o.z = fmaxf(acc[mt][nt][2] * inv + add, 0.f) * tsc;
            o.w = fmaxf(acc[mt][nt][3] * inv + add, 0.f) * tsc;
            *(float4*)(out + (size_t)(b * C_OUT + co) * HW + hw) = o;
        }
    }
}

// ---------------------------------------------------------------------------
extern "C" void kernel_launch(void* const* d_in, const int* in_sizes, int n_in,
                              void* d_out, int out_size, void* d_ws, size_t ws_size,
                              hipStream_t stream) {
    const float* x      = (const float*)d_in[0];
    const float* conv_w = (const float*)d_in[1];
    const float* gate_w = (const float*)d_in[2];
    const float* gate_b = (const float*)d_in[3];
    const float* bn_g   = (const float*)d_in[4];
    const float* bn_b   = (const float*)d_in[5];
    const float* bn_m   = (const float*)d_in[6];
    const float* bn_v   = (const float*)d_in[7];
    float* out = (float*)d_out;

    char* ws = (char*)d_ws;
    float*    s      = (float*)(ws + 0);          // 8192 f
    float*    tscale = (float*)(ws + 32768);      // 8192 f
    float*    bninv  = (float*)(ws + 65536);      // 256 f
    float*    bnadd  = (float*)(ws + 66560);      // 256 f
    ushort_t* Wt     = (ushort_t*)(ws + 67584);   // 589824 bf16
    ushort_t* xbp    = (ushort_t*)(ws + 1247232); // 32*58*58*256 bf16

    prep_w_kernel<<<2304, 256, 0, stream>>>(conv_w, bn_g, bn_b, bn_m, bn_v, Wt, bninv, bnadd, s);
    prep_x_kernel<<<dim3(4, 56, 32), 256, 0, stream>>>(x, xbp, s);
    gate_kernel<<<32, 256, 0, stream>>>(s, gate_w, gate_b, tscale);
    conv_kernel<<<1568, 256, 0, stream>>>(xbp, Wt, bninv, bnadd, tscale, out);
}